// Round 6
// baseline (1192.062 us; speedup 1.0000x reference)
//
#include <hip/hip_runtime.h>
#include <hip/hip_bf16.h>
#include <math.h>

#define NN 100000
#define NG 12500

using f32x4 = __attribute__((ext_vector_type(4))) float;
using bf16x8 = __attribute__((ext_vector_type(8))) __bf16;

__device__ __forceinline__ float warp_sum(float v) {
#pragma unroll
  for (int o = 32; o >= 1; o >>= 1) v += __shfl_xor(v, o);
  return v;
}

__device__ __forceinline__ float elu_f(float x) {
  return x > 0.f ? x : expm1f(x);
}

__device__ __forceinline__ ushort f2bf(float f) {
  unsigned u = __float_as_uint(f);
  u += 0x7FFFu + ((u >> 16) & 1u);
  return (ushort)(u >> 16);
}

// HW packed fp32->bf16 RNE: lo16 = bf16(a), hi16 = bf16(b)
__device__ __forceinline__ unsigned pkbf(float a, float b) {
  unsigned r;
  asm("v_cvt_pk_bf16_f32 %0, %1, %2" : "=v"(r) : "v"(a), "v"(b));
  return r;
}

// swizzled byte offset into a [row][64 bf16] LDS tile (row stride 128 B)
__device__ __forceinline__ int swz(int row, int kbyte) {
  return row * 128 + (kbyte ^ ((row & 7) << 4));
}

__global__ __launch_bounds__(256) void cvt_bf16(const float* __restrict__ src,
                                                ushort* __restrict__ dst, int n4) {
  int i = blockIdx.x * 256 + threadIdx.x;
  if (i >= n4) return;
  float4 v = *reinterpret_cast<const float4*>(src + (size_t)i * 4);
  ushort4 o;
  o.x = f2bf(v.x); o.y = f2bf(v.y); o.z = f2bf(v.z); o.w = f2bf(v.w);
  *reinterpret_cast<ushort4*>(dst + (size_t)i * 4) = o;
}

#define MM(i, j, a, b) \
  acc[i][j] = __builtin_amdgcn_mfma_f32_16x16x32_bf16(a, b, acc[i][j], 0, 0, 0)
#define MROW4(a0, a1, a2, a3, c0, c1, c2, c3)                 \
  MM(0, 0, a0, c0); MM(0, 1, a0, c1); MM(0, 2, a0, c2); MM(0, 3, a0, c3); \
  MM(1, 0, a1, c0); MM(1, 1, a1, c1); MM(1, 2, a1, c2); MM(1, 3, a1, c3); \
  MM(2, 0, a2, c0); MM(2, 1, a2, c1); MM(2, 2, a2, c2); MM(2, 3, a2, c3); \
  MM(3, 0, a3, c0); MM(3, 1, a3, c1); MM(3, 2, a3, c2); MM(3, 3, a3, c3);

// ---------------------------------------------------------------------------
// GEMM, A fp32 (depth-2 reg prefetch + cvt_pk -> dbuf LDS), B bf16 from L2.
// 256 thr = 4 waves (WR=1, WC=4): block tile 64 rows x 256 cols.
// PAIRED: ids differing by 8 share A-rows (same XCD -> L2 hit on 2nd read).
// ---------------------------------------------------------------------------
template<bool PAIRED, bool RELU>
__global__ __launch_bounds__(256, 3) void gemm_f32a(
    const float* __restrict__ A, const ushort* __restrict__ B,
    const float* __restrict__ bias, ushort* __restrict__ C,
    int M, int K, int Nc, int RB) {
  constexpr int BN = 256;
  __shared__ char smem[64 * (BN + 8) * 2];  // 33792 B; staging uses first 16 KB
  int rowb, colb;
  if (PAIRED) {
    int id = blockIdx.x;
    int full = ((2 * RB) >> 4) << 4;
    if (id < full) {
      rowb = ((id >> 4) << 3) + (id & 7);
      colb = (id >> 3) & 1;
    } else {
      int t = id - full;
      int tr = RB - (full >> 1);
      rowb = (full >> 1) + t % tr;
      colb = t / tr;
    }
  } else {
    rowb = blockIdx.x;
    colb = 0;
  }
  const int row0 = rowb * 64, col0 = colb * BN;
  const int tid = threadIdx.x, wid = tid >> 6, lane = tid & 63;
  const int lr = lane & 15, lg = lane >> 4;
  const int wn = wid * 64;
  // A staging: thread -> (row sr, 16-float chunk sc)
  const int sr = tid >> 2;
  const int sc = (tid & 3) << 4;
  const float* Ap = A + (size_t)(row0 + sr) * K + sc;
  const bool av = (row0 + sr) < M;
  const int wb0 = swz(sr, sc * 2), wb1 = swz(sr, sc * 2 + 16);
  // B fragment pointers (per lane; rows = output cols, contiguous 16B in k)
  const ushort* Bp0 = B + (size_t)(col0 + wn + 0 + lr) * K + lg * 8;
  const ushort* Bp1 = B + (size_t)(col0 + wn + 16 + lr) * K + lg * 8;
  const ushort* Bp2 = B + (size_t)(col0 + wn + 32 + lr) * K + lg * 8;
  const ushort* Bp3 = B + (size_t)(col0 + wn + 48 + lr) * K + lg * 8;

  float4 rA0, rA1, rA2, rA3, rB0, rB1, rB2, rB3;

#define LOADA(s0, s1, s2, s3, kt)                                       \
  do {                                                                  \
    if (av) {                                                           \
      const float* q = Ap + (kt);                                       \
      s0 = *reinterpret_cast<const float4*>(q);                         \
      s1 = *reinterpret_cast<const float4*>(q + 4);                     \
      s2 = *reinterpret_cast<const float4*>(q + 8);                     \
      s3 = *reinterpret_cast<const float4*>(q + 12);                    \
    } else {                                                            \
      s0 = s1 = s2 = s3 = make_float4(0.f, 0.f, 0.f, 0.f);              \
    }                                                                   \
  } while (0)

#define WRITEA(buf, s0, s1, s2, s3)                                     \
  do {                                                                  \
    uint4 ua, ub;                                                       \
    ua.x = pkbf(s0.x, s0.y); ua.y = pkbf(s0.z, s0.w);                   \
    ua.z = pkbf(s1.x, s1.y); ua.w = pkbf(s1.z, s1.w);                   \
    ub.x = pkbf(s2.x, s2.y); ub.y = pkbf(s2.z, s2.w);                   \
    ub.z = pkbf(s3.x, s3.y); ub.w = pkbf(s3.z, s3.w);                   \
    *reinterpret_cast<uint4*>((buf) + wb0) = ua;                        \
    *reinterpret_cast<uint4*>((buf) + wb1) = ub;                        \
  } while (0)

// One 64-k step: hoisted B loads -> A write (depth-2 regs) -> next A load ->
// two 32-k MFMA halves -> barrier.
#define KSTEP(cur, nxt, s0, s1, s2, s3, kt, kload)                           \
  do {                                                                       \
    bf16x8 b0 = *reinterpret_cast<const bf16x8*>(Bp0 + (kt));                \
    bf16x8 b1 = *reinterpret_cast<const bf16x8*>(Bp1 + (kt));                \
    bf16x8 b2 = *reinterpret_cast<const bf16x8*>(Bp2 + (kt));                \
    bf16x8 b3 = *reinterpret_cast<const bf16x8*>(Bp3 + (kt));                \
    bf16x8 b4 = *reinterpret_cast<const bf16x8*>(Bp0 + (kt) + 32);           \
    bf16x8 b5 = *reinterpret_cast<const bf16x8*>(Bp1 + (kt) + 32);           \
    bf16x8 b6 = *reinterpret_cast<const bf16x8*>(Bp2 + (kt) + 32);           \
    bf16x8 b7 = *reinterpret_cast<const bf16x8*>(Bp3 + (kt) + 32);           \
    if ((kt) + 64 < K) { WRITEA(nxt, s0, s1, s2, s3); }                      \
    if ((kload) < K) { LOADA(s0, s1, s2, s3, kload); }                       \
    {                                                                        \
      bf16x8 af0 = *reinterpret_cast<const bf16x8*>((cur) + swz(0 + lr, lg * 16));  \
      bf16x8 af1 = *reinterpret_cast<const bf16x8*>((cur) + swz(16 + lr, lg * 16)); \
      bf16x8 af2 = *reinterpret_cast<const bf16x8*>((cur) + swz(32 + lr, lg * 16)); \
      bf16x8 af3 = *reinterpret_cast<const bf16x8*>((cur) + swz(48 + lr, lg * 16)); \
      MROW4(af0, af1, af2, af3, b0, b1, b2, b3);                             \
      af0 = *reinterpret_cast<const bf16x8*>((cur) + swz(0 + lr, 64 + lg * 16));  \
      af1 = *reinterpret_cast<const bf16x8*>((cur) + swz(16 + lr, 64 + lg * 16)); \
      af2 = *reinterpret_cast<const bf16x8*>((cur) + swz(32 + lr, 64 + lg * 16)); \
      af3 = *reinterpret_cast<const bf16x8*>((cur) + swz(48 + lr, 64 + lg * 16)); \
      MROW4(af0, af1, af2, af3, b4, b5, b6, b7);                             \
    }                                                                        \
    __syncthreads();                                                         \
  } while (0)

  f32x4 acc[4][4] = {};
  char* buf0 = smem;
  char* buf1 = smem + 8192;
  // prologue: fill depth-2 pipeline
  LOADA(rA0, rA1, rA2, rA3, 0);
  LOADA(rB0, rB1, rB2, rB3, 64);
  WRITEA(buf0, rA0, rA1, rA2, rA3);
  LOADA(rA0, rA1, rA2, rA3, 128);
  __syncthreads();
  for (int kt = 0; kt < K; kt += 128) {
    KSTEP(buf0, buf1, rB0, rB1, rB2, rB3, kt, kt + 192);
    KSTEP(buf1, buf0, rA0, rA1, rA2, rA3, kt + 64, kt + 256);
  }
#undef LOADA
#undef WRITEA
#undef KSTEP
  // epilogue: acc -> LDS bf16 -> coalesced 16B stores
  ushort* Cs = reinterpret_cast<ushort*>(smem);
#pragma unroll
  for (int j = 0; j < 4; ++j) {
    float bv = bias ? bias[col0 + wn + j * 16 + lr] : 0.f;
#pragma unroll
    for (int i = 0; i < 4; ++i)
#pragma unroll
      for (int r = 0; r < 4; ++r) {
        float v = acc[i][j][r] + bv;
        if (RELU) v = fmaxf(v, 0.f);
        Cs[(i * 16 + lg * 4 + r) * (BN + 8) + wn + j * 16 + lr] = f2bf(v);
      }
  }
  __syncthreads();
#pragma unroll
  for (int u = 0; u < 8; ++u) {
    int unit = tid + u * 256;
    int r = unit >> 5, cg = unit & 31;  // BN/8 = 32
    int grow = row0 + r;
    if (grow < M)
      *reinterpret_cast<uint4*>(C + (size_t)grow * Nc + col0 + cg * 8) =
          *reinterpret_cast<const uint4*>(Cs + r * (BN + 8) + cg * 8);
  }
}

// ---------------------------------------------------------------------------
// GEMM, A bf16 staged via global_load_lds (pre-swizzled global src, linear LDS
// dest), B direct from L2. 256 thr = 4 waves (WR=2, WC=2): tile 128 x 128.
// ---------------------------------------------------------------------------
template<bool RELU>
__global__ __launch_bounds__(256, 3) void gemm_bf16a(
    const ushort* __restrict__ A, const ushort* __restrict__ B,
    const float* __restrict__ bias, ushort* __restrict__ C,
    int M, int K, int Nc) {
  constexpr int BN = 128;
  __shared__ char smem[128 * (BN + 8) * 2];  // 34816 B >= 2 * 16384 staging
  const int row0 = blockIdx.x * 128;
  const int tid = threadIdx.x, wid = tid >> 6, lane = tid & 63;
  const int lr = lane & 15, lg = lane >> 4;
  const int wm = (wid >> 1) * 64, wn = (wid & 1) * 64;
  const ushort* Bp0 = B + (size_t)(wn + 0 + lr) * K + lg * 8;
  const ushort* Bp1 = B + (size_t)(wn + 16 + lr) * K + lg * 8;
  const ushort* Bp2 = B + (size_t)(wn + 32 + lr) * K + lg * 8;
  const ushort* Bp3 = B + (size_t)(wn + 48 + lr) * K + lg * 8;

#define STAGE(buf, kt)                                                          \
  do {                                                                          \
    _Pragma("unroll")                                                           \
    for (int u = 0; u < 4; ++u) {                                               \
      int unit = u * 256 + tid;                                                 \
      int drow = unit >> 3, dkg = unit & 7;                                     \
      const ushort* src = A + (size_t)(row0 + drow) * K + (kt) +                \
                          (((dkg * 16) ^ ((drow & 7) << 4)) >> 1);              \
      if (row0 + drow < M)                                                      \
        __builtin_amdgcn_global_load_lds(src, (buf) + u * 4096 + wid * 1024,    \
                                         16, 0, 0);                             \
    }                                                                           \
  } while (0)

  f32x4 acc[4][4] = {};
  STAGE(smem, 0);
  __syncthreads();
  for (int kt = 0; kt < K; kt += 64) {
    int pb = (kt >> 6) & 1;
    char* cur = smem + pb * 16384;
    char* nxt = smem + (pb ^ 1) * 16384;
    if (kt + 64 < K) STAGE(nxt, kt + 64);
    bf16x8 b0 = *reinterpret_cast<const bf16x8*>(Bp0 + kt);
    bf16x8 b1 = *reinterpret_cast<const bf16x8*>(Bp1 + kt);
    bf16x8 b2 = *reinterpret_cast<const bf16x8*>(Bp2 + kt);
    bf16x8 b3 = *reinterpret_cast<const bf16x8*>(Bp3 + kt);
    bf16x8 b4 = *reinterpret_cast<const bf16x8*>(Bp0 + kt + 32);
    bf16x8 b5 = *reinterpret_cast<const bf16x8*>(Bp1 + kt + 32);
    bf16x8 b6 = *reinterpret_cast<const bf16x8*>(Bp2 + kt + 32);
    bf16x8 b7 = *reinterpret_cast<const bf16x8*>(Bp3 + kt + 32);
    {
      bf16x8 af0 = *reinterpret_cast<const bf16x8*>(cur + swz(wm + 0 + lr, lg * 16));
      bf16x8 af1 = *reinterpret_cast<const bf16x8*>(cur + swz(wm + 16 + lr, lg * 16));
      bf16x8 af2 = *reinterpret_cast<const bf16x8*>(cur + swz(wm + 32 + lr, lg * 16));
      bf16x8 af3 = *reinterpret_cast<const bf16x8*>(cur + swz(wm + 48 + lr, lg * 16));
      MROW4(af0, af1, af2, af3, b0, b1, b2, b3);
      af0 = *reinterpret_cast<const bf16x8*>(cur + swz(wm + 0 + lr, 64 + lg * 16));
      af1 = *reinterpret_cast<const bf16x8*>(cur + swz(wm + 16 + lr, 64 + lg * 16));
      af2 = *reinterpret_cast<const bf16x8*>(cur + swz(wm + 32 + lr, 64 + lg * 16));
      af3 = *reinterpret_cast<const bf16x8*>(cur + swz(wm + 48 + lr, 64 + lg * 16));
      MROW4(af0, af1, af2, af3, b4, b5, b6, b7);
    }
    __syncthreads();
  }
#undef STAGE
  ushort* Cs = reinterpret_cast<ushort*>(smem);
#pragma unroll
  for (int j = 0; j < 4; ++j) {
    float bv = bias ? bias[wn + j * 16 + lr] : 0.f;
#pragma unroll
    for (int i = 0; i < 4; ++i)
#pragma unroll
      for (int r = 0; r < 4; ++r) {
        float v = acc[i][j][r] + bv;
        if (RELU) v = fmaxf(v, 0.f);
        Cs[(wm + i * 16 + lg * 4 + r) * (BN + 8) + wn + j * 16 + lr] = f2bf(v);
      }
  }
  __syncthreads();
#pragma unroll
  for (int u = 0; u < 8; ++u) {
    int unit = tid + u * 256;
    int r = unit >> 4, cg = unit & 15;  // BN/8 = 16
    int grow = row0 + r;
    if (grow < M)
      *reinterpret_cast<uint4*>(C + (size_t)grow * Nc + cg * 8) =
          *reinterpret_cast<const uint4*>(Cs + r * (BN + 8) + cg * 8);
  }
}

// x[:,0:128] = cat_table[cat_ids]; x[:,128:256] = LN(v2 bf16)
__global__ __launch_bounds__(256) void ln_concat(const ushort* __restrict__ v2,
    const float* __restrict__ g, const float* __restrict__ b,
    const int* __restrict__ cat_ids, const float* __restrict__ cat_table,
    float* __restrict__ x) {
  int w = (blockIdx.x * blockDim.x + threadIdx.x) >> 6;
  int lane = threadIdx.x & 63;
  if (w >= NN) return;
  unsigned raw = *reinterpret_cast<const unsigned*>(v2 + (size_t)w * 128 + lane * 2);
  float ax = __uint_as_float(raw << 16);
  float ay = __uint_as_float(raw & 0xFFFF0000u);
  float s = ax + ay, s2 = ax * ax + ay * ay;
  s = warp_sum(s); s2 = warp_sum(s2);
  float mu = s * (1.f / 128.f);
  float var = s2 * (1.f / 128.f) - mu * mu;
  float rs = rsqrtf(var + 1e-5f);
  float2 gg = *reinterpret_cast<const float2*>(g + lane * 2);
  float2 bb = *reinterpret_cast<const float2*>(b + lane * 2);
  float2 o;
  o.x = (ax - mu) * rs * gg.x + bb.x;
  o.y = (ay - mu) * rs * gg.y + bb.y;
  *reinterpret_cast<float2*>(x + (size_t)w * 256 + 128 + lane * 2) = o;
  int cid = cat_ids[w];
  *reinterpret_cast<float2*>(x + (size_t)w * 256 + lane * 2) =
      *reinterpret_cast<const float2*>(cat_table + (size_t)cid * 128 + lane * 2);
}

// fused GAT: scores + 8x8 softmax + aggregate + bias + elu + residual + LN.
template<int H>
__global__ __launch_bounds__(256) void gat_fused(const ushort* __restrict__ h,
    const float* __restrict__ asv, const float* __restrict__ adv,
    const float* __restrict__ bias, const float* __restrict__ lng,
    const float* __restrict__ lnb, float* __restrict__ x) {
  constexpr int C = 256 / H;
  constexpr int GROUP = C / 4;
  __shared__ __align__(16) float hs[4][8][256];
  __shared__ float attS[4][8][H], attD[4][8][H];
  const int wid = threadIdx.x >> 6, lane = threadIdx.x & 63;
  const int g = blockIdx.x * 4 + wid;
  const int base = g * 8;
  const int hd = lane / GROUP;
  float4 as4 = *reinterpret_cast<const float4*>(asv + lane * 4);
  float4 ad4 = *reinterpret_cast<const float4*>(adv + lane * 4);
#pragma unroll
  for (int i = 0; i < 8; ++i) {
    uint2 raw = *reinterpret_cast<const uint2*>(h + (size_t)(base + i) * 256 + lane * 4);
    float f0 = __uint_as_float(raw.x << 16);
    float f1 = __uint_as_float(raw.x & 0xFFFF0000u);
    float f2 = __uint_as_float(raw.y << 16);
    float f3 = __uint_as_float(raw.y & 0xFFFF0000u);
    *reinterpret_cast<float4*>(&hs[wid][i][lane * 4]) = make_float4(f0, f1, f2, f3);
    float ps = f0 * as4.x + f1 * as4.y + f2 * as4.z + f3 * as4.w;
    float pd = f0 * ad4.x + f1 * ad4.y + f2 * ad4.z + f3 * ad4.w;
#pragma unroll
    for (int o = GROUP / 2; o >= 1; o >>= 1) {
      ps += __shfl_xor(ps, o);
      pd += __shfl_xor(pd, o);
    }
    if ((lane & (GROUP - 1)) == 0) {
      attS[wid][i][hd] = ps;
      attD[wid][i][hd] = pd;
    }
  }
  __syncthreads();
  const float4 gv = *reinterpret_cast<const float4*>(lng + lane * 4);
  const float4 bv = *reinterpret_cast<const float4*>(lnb + lane * 4);
  const float4 biasv = *reinterpret_cast<const float4*>(bias + lane * 4);
  for (int i = 0; i < 8; ++i) {
    float ad = attD[wid][i][hd];
    float e[8];
    float mx = -1e30f;
#pragma unroll
    for (int j = 0; j < 8; ++j) {
      float v = attS[wid][j][hd] + ad;
      v = v > 0.f ? v : 0.2f * v;
      e[j] = v;
      mx = fmaxf(mx, v);
    }
    float sum = 0.f;
#pragma unroll
    for (int j = 0; j < 8; ++j) { e[j] = expf(e[j] - mx); sum += e[j]; }
    float inv = 1.f / (sum + 1e-16f);
    float a0 = 0, a1 = 0, a2 = 0, a3 = 0;
#pragma unroll
    for (int j = 0; j < 8; ++j) {
      float wj = e[j] * inv;
      float4 hv = *reinterpret_cast<const float4*>(&hs[wid][j][lane * 4]);
      a0 += wj * hv.x; a1 += wj * hv.y; a2 += wj * hv.z; a3 += wj * hv.w;
    }
    float4 xr = *reinterpret_cast<const float4*>(x + (size_t)(base + i) * 256 + lane * 4);
    float v0 = elu_f(a0 + biasv.x) + xr.x;
    float v1 = elu_f(a1 + biasv.y) + xr.y;
    float v2 = elu_f(a2 + biasv.z) + xr.z;
    float v3 = elu_f(a3 + biasv.w) + xr.w;
    float s = v0 + v1 + v2 + v3;
    float s2 = v0 * v0 + v1 * v1 + v2 * v2 + v3 * v3;
    s = warp_sum(s); s2 = warp_sum(s2);
    float mu = s * (1.f / 256.f);
    float var = s2 * (1.f / 256.f) - mu * mu;
    float rs = rsqrtf(var + 1e-5f);
    float4 o;
    o.x = (v0 - mu) * rs * gv.x + bv.x;
    o.y = (v1 - mu) * rs * gv.y + bv.y;
    o.z = (v2 - mu) * rs * gv.z + bv.z;
    o.w = (v3 - mu) * rs * gv.w + bv.w;
    *reinterpret_cast<float4*>(x + (size_t)(base + i) * 256 + lane * 4) = o;
  }
}

__global__ __launch_bounds__(256) void pool_readout(const float* __restrict__ x,
    const float* __restrict__ rw, const float* __restrict__ rb,
    float* __restrict__ out) {
  int g = (blockIdx.x * blockDim.x + threadIdx.x) >> 6;
  int lane = threadIdx.x & 63;
  if (g >= NG) return;
  float a0 = 0, a1 = 0, a2 = 0, a3 = 0;
#pragma unroll
  for (int j = 0; j < 8; ++j) {
    float4 v = *reinterpret_cast<const float4*>(x + (size_t)(g * 8 + j) * 256 + lane * 4);
    a0 += v.x; a1 += v.y; a2 += v.z; a3 += v.w;
  }
  float4 w = *reinterpret_cast<const float4*>(rw + lane * 4);
  float p = (a0 * w.x + a1 * w.y + a2 * w.z + a3 * w.w) * 0.125f;
  p = warp_sum(p);
  if (lane == 0) out[g] = 1.f / (1.f + expf(-(p + rb[0])));
}

extern "C" void kernel_launch(void* const* d_in, const int* in_sizes, int n_in,
                              void* d_out, int out_size, void* d_ws, size_t ws_size,
                              hipStream_t stream) {
  const int* cat_ids = (const int*)d_in[0];
  const float* vf = (const float*)d_in[1];
  const float* cat_table = (const float*)d_in[4];
  const float* vp_w1 = (const float*)d_in[5];
  const float* vp_b1 = (const float*)d_in[6];
  const float* vp_w2 = (const float*)d_in[7];
  const float* vp_b2 = (const float*)d_in[8];
  const float* vp_lng = (const float*)d_in[9];
  const float* vp_lnb = (const float*)d_in[10];
  const float* c0_w = (const float*)d_in[11];
  const float* c0_as = (const float*)d_in[12];
  const float* c0_ad = (const float*)d_in[13];
  const float* c0_b = (const float*)d_in[14];
  const float* ln0_g = (const float*)d_in[15];
  const float* ln0_b = (const float*)d_in[16];
  const float* c1_w = (const float*)d_in[17];
  const float* c1_as = (const float*)d_in[18];
  const float* c1_ad = (const float*)d_in[19];
  const float* c1_b = (const float*)d_in[20];
  const float* ln1_g = (const float*)d_in[21];
  const float* ln1_b = (const float*)d_in[22];
  const float* ro_w = (const float*)d_in[23];
  const float* ro_b = (const float*)d_in[24];
  float* out = (float*)d_out;

  char* ws = (char*)d_ws;
  ushort* w1b = (ushort*)ws;   ws += (size_t)512 * 2048 * 2;
  ushort* w2b = (ushort*)ws;   ws += (size_t)128 * 512 * 2;
  ushort* c0wb = (ushort*)ws;  ws += (size_t)256 * 256 * 2;
  ushort* c1wb = (ushort*)ws;  ws += (size_t)256 * 256 * 2;
  ushort* v1b = (ushort*)ws;   ws += (size_t)NN * 512 * 2;
  ushort* v2b = (ushort*)ws;   ws += (size_t)NN * 128 * 2;
  ushort* hbb = (ushort*)ws;   ws += (size_t)NN * 256 * 2;
  float* xb = (float*)ws;

  dim3 b256(256);
  const int RB = (NN + 63) / 64;  // 1563 row blocks of 64

  cvt_bf16<<<1024, b256, 0, stream>>>(vp_w1, w1b, 512 * 2048 / 4);
  cvt_bf16<<<64, b256, 0, stream>>>(vp_w2, w2b, 128 * 512 / 4);
  cvt_bf16<<<64, b256, 0, stream>>>(c0_w, c0wb, 256 * 256 / 4);
  cvt_bf16<<<64, b256, 0, stream>>>(c1_w, c1wb, 256 * 256 / 4);

  // v1 = relu(vf @ w1^T + b1): 64x256 tiles, 2 col-blocks paired on same XCD
  gemm_f32a<true, true><<<2 * RB, b256, 0, stream>>>(vf, w1b, vp_b1, v1b,
                                                     NN, 2048, 512, RB);
  // v2 = v1 @ w2^T + b2
  gemm_bf16a<false><<<(NN + 127) / 128, b256, 0, stream>>>(v1b, w2b, vp_b2, v2b,
                                                           NN, 512, 128);
  ln_concat<<<(NN * 64 + 255) / 256, b256, 0, stream>>>(v2b, vp_lng, vp_lnb,
                                                        cat_ids, cat_table, xb);

  gemm_f32a<false, false><<<RB, b256, 0, stream>>>(xb, c0wb, nullptr, hbb,
                                                   NN, 256, 256, 0);
  gat_fused<4><<<NG / 4, b256, 0, stream>>>(hbb, c0_as, c0_ad, c0_b, ln0_g, ln0_b, xb);

  gemm_f32a<false, false><<<RB, b256, 0, stream>>>(xb, c1wb, nullptr, hbb,
                                                   NN, 256, 256, 0);
  gat_fused<1><<<NG / 4, b256, 0, stream>>>(hbb, c1_as, c1_ad, c1_b, ln1_g, ln1_b, xb);

  pool_readout<<<NG / 4, b256, 0, stream>>>(xb, ro_w, ro_b, out);
}

// Round 7
// 831.329 us; speedup vs baseline: 1.4339x; 1.4339x over previous
//
#include <hip/hip_runtime.h>
#include <hip/hip_bf16.h>
#include <math.h>

#define NN 100000
#define NG 12500

using f32x4 = __attribute__((ext_vector_type(4))) float;
using bf16x8 = __attribute__((ext_vector_type(8))) __bf16;

__device__ __forceinline__ float warp_sum(float v) {
#pragma unroll
  for (int o = 32; o >= 1; o >>= 1) v += __shfl_xor(v, o);
  return v;
}

__device__ __forceinline__ float elu_f(float x) {
  return x > 0.f ? x : expm1f(x);
}

__device__ __forceinline__ ushort f2bf(float f) {
  unsigned u = __float_as_uint(f);
  u += 0x7FFFu + ((u >> 16) & 1u);
  return (ushort)(u >> 16);
}

// HW packed fp32->bf16 RNE: lo16 = bf16(a), hi16 = bf16(b)
__device__ __forceinline__ unsigned pkbf(float a, float b) {
  unsigned r;
  asm("v_cvt_pk_bf16_f32 %0, %1, %2" : "=v"(r) : "v"(a), "v"(b));
  return r;
}

// swizzled byte offset into a [row][64 bf16] LDS tile (row stride 128 B)
__device__ __forceinline__ int swz(int row, int kbyte) {
  return row * 128 + (kbyte ^ ((row & 7) << 4));
}

__global__ __launch_bounds__(256) void cvt_bf16(const float* __restrict__ src,
                                                ushort* __restrict__ dst, int n4) {
  int i = blockIdx.x * 256 + threadIdx.x;
  if (i >= n4) return;
  float4 v = *reinterpret_cast<const float4*>(src + (size_t)i * 4);
  ushort4 o;
  o.x = f2bf(v.x); o.y = f2bf(v.y); o.z = f2bf(v.z); o.w = f2bf(v.w);
  *reinterpret_cast<ushort4*>(dst + (size_t)i * 4) = o;
}

#define MM(i, j, a, b) \
  acc[i][j] = __builtin_amdgcn_mfma_f32_16x16x32_bf16(a, b, acc[i][j], 0, 0, 0)
#define MROW4(a0, a1, a2, a3, c0, c1, c2, c3)                 \
  MM(0, 0, a0, c0); MM(0, 1, a0, c1); MM(0, 2, a0, c2); MM(0, 3, a0, c3); \
  MM(1, 0, a1, c0); MM(1, 1, a1, c1); MM(1, 2, a1, c2); MM(1, 3, a1, c3); \
  MM(2, 0, a2, c0); MM(2, 1, a2, c1); MM(2, 2, a2, c2); MM(2, 3, a2, c3); \
  MM(3, 0, a3, c0); MM(3, 1, a3, c1); MM(3, 2, a3, c2); MM(3, 3, a3, c3);

// ---------------------------------------------------------------------------
// GEMM, A fp32 (depth-2 reg prefetch + cvt_pk -> dbuf LDS), B bf16 from L2.
// 256 thr = 4 waves (WR=1, WC=4): block tile 64 rows x 256 cols.
// PAIRED: ids differing by 8 share A-rows (same XCD -> L2 hit on 2nd read).
// launch_bounds(256,2): depth-2 needs ~190 VGPR; (256,3) forced scratch spill
// (R6: WRITE_SIZE 8x, GEMM1 875us).
// ---------------------------------------------------------------------------
template<bool PAIRED, bool RELU>
__global__ __launch_bounds__(256, 2) void gemm_f32a(
    const float* __restrict__ A, const ushort* __restrict__ B,
    const float* __restrict__ bias, ushort* __restrict__ C,
    int M, int K, int Nc, int RB) {
  constexpr int BN = 256;
  __shared__ char smem[64 * (BN + 8) * 2];  // 33792 B; staging uses first 16 KB
  int rowb, colb;
  if (PAIRED) {
    int id = blockIdx.x;
    int full = ((2 * RB) >> 4) << 4;
    if (id < full) {
      rowb = ((id >> 4) << 3) + (id & 7);
      colb = (id >> 3) & 1;
    } else {
      int t = id - full;
      int tr = RB - (full >> 1);
      rowb = (full >> 1) + t % tr;
      colb = t / tr;
    }
  } else {
    rowb = blockIdx.x;
    colb = 0;
  }
  const int row0 = rowb * 64, col0 = colb * BN;
  const int tid = threadIdx.x, wid = tid >> 6, lane = tid & 63;
  const int lr = lane & 15, lg = lane >> 4;
  const int wn = wid * 64;
  // A staging: thread -> (row sr, 16-float chunk sc)
  const int sr = tid >> 2;
  const int sc = (tid & 3) << 4;
  const float* Ap = A + (size_t)(row0 + sr) * K + sc;
  const bool av = (row0 + sr) < M;
  const int wb0 = swz(sr, sc * 2), wb1 = swz(sr, sc * 2 + 16);
  // B fragment pointers (per lane; rows = output cols, contiguous 16B in k)
  const ushort* Bp0 = B + (size_t)(col0 + wn + 0 + lr) * K + lg * 8;
  const ushort* Bp1 = B + (size_t)(col0 + wn + 16 + lr) * K + lg * 8;
  const ushort* Bp2 = B + (size_t)(col0 + wn + 32 + lr) * K + lg * 8;
  const ushort* Bp3 = B + (size_t)(col0 + wn + 48 + lr) * K + lg * 8;

  float4 rA0, rA1, rA2, rA3, rB0, rB1, rB2, rB3;

#define LOADA(s0, s1, s2, s3, kt)                                       \
  do {                                                                  \
    if (av) {                                                           \
      const float* q = Ap + (kt);                                       \
      s0 = *reinterpret_cast<const float4*>(q);                         \
      s1 = *reinterpret_cast<const float4*>(q + 4);                     \
      s2 = *reinterpret_cast<const float4*>(q + 8);                     \
      s3 = *reinterpret_cast<const float4*>(q + 12);                    \
    } else {                                                            \
      s0 = s1 = s2 = s3 = make_float4(0.f, 0.f, 0.f, 0.f);              \
    }                                                                   \
  } while (0)

#define WRITEA(buf, s0, s1, s2, s3)                                     \
  do {                                                                  \
    uint4 ua, ub;                                                       \
    ua.x = pkbf(s0.x, s0.y); ua.y = pkbf(s0.z, s0.w);                   \
    ua.z = pkbf(s1.x, s1.y); ua.w = pkbf(s1.z, s1.w);                   \
    ub.x = pkbf(s2.x, s2.y); ub.y = pkbf(s2.z, s2.w);                   \
    ub.z = pkbf(s3.x, s3.y); ub.w = pkbf(s3.z, s3.w);                   \
    *reinterpret_cast<uint4*>((buf) + wb0) = ua;                        \
    *reinterpret_cast<uint4*>((buf) + wb1) = ub;                        \
  } while (0)

// One 64-k step: hoisted B loads -> A write (depth-2 regs) -> next A load ->
// two 32-k MFMA halves -> barrier.
#define KSTEP(cur, nxt, s0, s1, s2, s3, kt, kload)                           \
  do {                                                                       \
    bf16x8 b0 = *reinterpret_cast<const bf16x8*>(Bp0 + (kt));                \
    bf16x8 b1 = *reinterpret_cast<const bf16x8*>(Bp1 + (kt));                \
    bf16x8 b2 = *reinterpret_cast<const bf16x8*>(Bp2 + (kt));                \
    bf16x8 b3 = *reinterpret_cast<const bf16x8*>(Bp3 + (kt));                \
    bf16x8 b4 = *reinterpret_cast<const bf16x8*>(Bp0 + (kt) + 32);           \
    bf16x8 b5 = *reinterpret_cast<const bf16x8*>(Bp1 + (kt) + 32);           \
    bf16x8 b6 = *reinterpret_cast<const bf16x8*>(Bp2 + (kt) + 32);           \
    bf16x8 b7 = *reinterpret_cast<const bf16x8*>(Bp3 + (kt) + 32);           \
    if ((kt) + 64 < K) { WRITEA(nxt, s0, s1, s2, s3); }                      \
    if ((kload) < K) { LOADA(s0, s1, s2, s3, kload); }                       \
    {                                                                        \
      bf16x8 af0 = *reinterpret_cast<const bf16x8*>((cur) + swz(0 + lr, lg * 16));  \
      bf16x8 af1 = *reinterpret_cast<const bf16x8*>((cur) + swz(16 + lr, lg * 16)); \
      bf16x8 af2 = *reinterpret_cast<const bf16x8*>((cur) + swz(32 + lr, lg * 16)); \
      bf16x8 af3 = *reinterpret_cast<const bf16x8*>((cur) + swz(48 + lr, lg * 16)); \
      MROW4(af0, af1, af2, af3, b0, b1, b2, b3);                             \
      af0 = *reinterpret_cast<const bf16x8*>((cur) + swz(0 + lr, 64 + lg * 16));  \
      af1 = *reinterpret_cast<const bf16x8*>((cur) + swz(16 + lr, 64 + lg * 16)); \
      af2 = *reinterpret_cast<const bf16x8*>((cur) + swz(32 + lr, 64 + lg * 16)); \
      af3 = *reinterpret_cast<const bf16x8*>((cur) + swz(48 + lr, 64 + lg * 16)); \
      MROW4(af0, af1, af2, af3, b4, b5, b6, b7);                             \
    }                                                                        \
    __syncthreads();                                                         \
  } while (0)

  f32x4 acc[4][4] = {};
  char* buf0 = smem;
  char* buf1 = smem + 8192;
  // prologue: fill depth-2 pipeline
  LOADA(rA0, rA1, rA2, rA3, 0);
  LOADA(rB0, rB1, rB2, rB3, 64);
  WRITEA(buf0, rA0, rA1, rA2, rA3);
  LOADA(rA0, rA1, rA2, rA3, 128);
  __syncthreads();
  for (int kt = 0; kt < K; kt += 128) {
    KSTEP(buf0, buf1, rB0, rB1, rB2, rB3, kt, kt + 192);
    KSTEP(buf1, buf0, rA0, rA1, rA2, rA3, kt + 64, kt + 256);
  }
#undef LOADA
#undef WRITEA
#undef KSTEP
  // epilogue: acc -> LDS bf16 -> coalesced 16B stores
  ushort* Cs = reinterpret_cast<ushort*>(smem);
#pragma unroll
  for (int j = 0; j < 4; ++j) {
    float bv = bias ? bias[col0 + wn + j * 16 + lr] : 0.f;
#pragma unroll
    for (int i = 0; i < 4; ++i)
#pragma unroll
      for (int r = 0; r < 4; ++r) {
        float v = acc[i][j][r] + bv;
        if (RELU) v = fmaxf(v, 0.f);
        Cs[(i * 16 + lg * 4 + r) * (BN + 8) + wn + j * 16 + lr] = f2bf(v);
      }
  }
  __syncthreads();
#pragma unroll
  for (int u = 0; u < 8; ++u) {
    int unit = tid + u * 256;
    int r = unit >> 5, cg = unit & 31;  // BN/8 = 32
    int grow = row0 + r;
    if (grow < M)
      *reinterpret_cast<uint4*>(C + (size_t)grow * Nc + col0 + cg * 8) =
          *reinterpret_cast<const uint4*>(Cs + r * (BN + 8) + cg * 8);
  }
}

// ---------------------------------------------------------------------------
// GEMM, A bf16 staged via global_load_lds (pre-swizzled global src, linear LDS
// dest), B direct from L2. 256 thr = 4 waves (WR=2, WC=2): tile 128 x 128.
// ---------------------------------------------------------------------------
template<bool RELU>
__global__ __launch_bounds__(256, 3) void gemm_bf16a(
    const ushort* __restrict__ A, const ushort* __restrict__ B,
    const float* __restrict__ bias, ushort* __restrict__ C,
    int M, int K, int Nc) {
  constexpr int BN = 128;
  __shared__ char smem[128 * (BN + 8) * 2];  // 34816 B >= 2 * 16384 staging
  const int row0 = blockIdx.x * 128;
  const int tid = threadIdx.x, wid = tid >> 6, lane = tid & 63;
  const int lr = lane & 15, lg = lane >> 4;
  const int wm = (wid >> 1) * 64, wn = (wid & 1) * 64;
  const ushort* Bp0 = B + (size_t)(wn + 0 + lr) * K + lg * 8;
  const ushort* Bp1 = B + (size_t)(wn + 16 + lr) * K + lg * 8;
  const ushort* Bp2 = B + (size_t)(wn + 32 + lr) * K + lg * 8;
  const ushort* Bp3 = B + (size_t)(wn + 48 + lr) * K + lg * 8;

#define STAGE(buf, kt)                                                          \
  do {                                                                          \
    _Pragma("unroll")                                                           \
    for (int u = 0; u < 4; ++u) {                                               \
      int unit = u * 256 + tid;                                                 \
      int drow = unit >> 3, dkg = unit & 7;                                     \
      const ushort* src = A + (size_t)(row0 + drow) * K + (kt) +                \
                          (((dkg * 16) ^ ((drow & 7) << 4)) >> 1);              \
      if (row0 + drow < M)                                                      \
        __builtin_amdgcn_global_load_lds(src, (buf) + u * 4096 + wid * 1024,    \
                                         16, 0, 0);                             \
    }                                                                           \
  } while (0)

  f32x4 acc[4][4] = {};
  STAGE(smem, 0);
  __syncthreads();
  for (int kt = 0; kt < K; kt += 64) {
    int pb = (kt >> 6) & 1;
    char* cur = smem + pb * 16384;
    char* nxt = smem + (pb ^ 1) * 16384;
    if (kt + 64 < K) STAGE(nxt, kt + 64);
    bf16x8 b0 = *reinterpret_cast<const bf16x8*>(Bp0 + kt);
    bf16x8 b1 = *reinterpret_cast<const bf16x8*>(Bp1 + kt);
    bf16x8 b2 = *reinterpret_cast<const bf16x8*>(Bp2 + kt);
    bf16x8 b3 = *reinterpret_cast<const bf16x8*>(Bp3 + kt);
    bf16x8 b4 = *reinterpret_cast<const bf16x8*>(Bp0 + kt + 32);
    bf16x8 b5 = *reinterpret_cast<const bf16x8*>(Bp1 + kt + 32);
    bf16x8 b6 = *reinterpret_cast<const bf16x8*>(Bp2 + kt + 32);
    bf16x8 b7 = *reinterpret_cast<const bf16x8*>(Bp3 + kt + 32);
    {
      bf16x8 af0 = *reinterpret_cast<const bf16x8*>(cur + swz(wm + 0 + lr, lg * 16));
      bf16x8 af1 = *reinterpret_cast<const bf16x8*>(cur + swz(wm + 16 + lr, lg * 16));
      bf16x8 af2 = *reinterpret_cast<const bf16x8*>(cur + swz(wm + 32 + lr, lg * 16));
      bf16x8 af3 = *reinterpret_cast<const bf16x8*>(cur + swz(wm + 48 + lr, lg * 16));
      MROW4(af0, af1, af2, af3, b0, b1, b2, b3);
      af0 = *reinterpret_cast<const bf16x8*>(cur + swz(wm + 0 + lr, 64 + lg * 16));
      af1 = *reinterpret_cast<const bf16x8*>(cur + swz(wm + 16 + lr, 64 + lg * 16));
      af2 = *reinterpret_cast<const bf16x8*>(cur + swz(wm + 32 + lr, 64 + lg * 16));
      af3 = *reinterpret_cast<const bf16x8*>(cur + swz(wm + 48 + lr, 64 + lg * 16));
      MROW4(af0, af1, af2, af3, b4, b5, b6, b7);
    }
    __syncthreads();
  }
#undef STAGE
  ushort* Cs = reinterpret_cast<ushort*>(smem);
#pragma unroll
  for (int j = 0; j < 4; ++j) {
    float bv = bias ? bias[wn + j * 16 + lr] : 0.f;
#pragma unroll
    for (int i = 0; i < 4; ++i)
#pragma unroll
      for (int r = 0; r < 4; ++r) {
        float v = acc[i][j][r] + bv;
        if (RELU) v = fmaxf(v, 0.f);
        Cs[(wm + i * 16 + lg * 4 + r) * (BN + 8) + wn + j * 16 + lr] = f2bf(v);
      }
  }
  __syncthreads();
#pragma unroll
  for (int u = 0; u < 8; ++u) {
    int unit = tid + u * 256;
    int r = unit >> 4, cg = unit & 15;  // BN/8 = 16
    int grow = row0 + r;
    if (grow < M)
      *reinterpret_cast<uint4*>(C + (size_t)grow * Nc + cg * 8) =
          *reinterpret_cast<const uint4*>(Cs + r * (BN + 8) + cg * 8);
  }
}

// x[:,0:128] = cat_table[cat_ids]; x[:,128:256] = LN(v2 bf16)
__global__ __launch_bounds__(256) void ln_concat(const ushort* __restrict__ v2,
    const float* __restrict__ g, const float* __restrict__ b,
    const int* __restrict__ cat_ids, const float* __restrict__ cat_table,
    float* __restrict__ x) {
  int w = (blockIdx.x * blockDim.x + threadIdx.x) >> 6;
  int lane = threadIdx.x & 63;
  if (w >= NN) return;
  unsigned raw = *reinterpret_cast<const unsigned*>(v2 + (size_t)w * 128 + lane * 2);
  float ax = __uint_as_float(raw << 16);
  float ay = __uint_as_float(raw & 0xFFFF0000u);
  float s = ax + ay, s2 = ax * ax + ay * ay;
  s = warp_sum(s); s2 = warp_sum(s2);
  float mu = s * (1.f / 128.f);
  float var = s2 * (1.f / 128.f) - mu * mu;
  float rs = rsqrtf(var + 1e-5f);
  float2 gg = *reinterpret_cast<const float2*>(g + lane * 2);
  float2 bb = *reinterpret_cast<const float2*>(b + lane * 2);
  float2 o;
  o.x = (ax - mu) * rs * gg.x + bb.x;
  o.y = (ay - mu) * rs * gg.y + bb.y;
  *reinterpret_cast<float2*>(x + (size_t)w * 256 + 128 + lane * 2) = o;
  int cid = cat_ids[w];
  *reinterpret_cast<float2*>(x + (size_t)w * 256 + lane * 2) =
      *reinterpret_cast<const float2*>(cat_table + (size_t)cid * 128 + lane * 2);
}

// fused GAT: scores + 8x8 softmax + aggregate + bias + elu + residual + LN.
template<int H>
__global__ __launch_bounds__(256) void gat_fused(const ushort* __restrict__ h,
    const float* __restrict__ asv, const float* __restrict__ adv,
    const float* __restrict__ bias, const float* __restrict__ lng,
    const float* __restrict__ lnb, float* __restrict__ x) {
  constexpr int C = 256 / H;
  constexpr int GROUP = C / 4;
  __shared__ __align__(16) float hs[4][8][256];
  __shared__ float attS[4][8][H], attD[4][8][H];
  const int wid = threadIdx.x >> 6, lane = threadIdx.x & 63;
  const int g = blockIdx.x * 4 + wid;
  const int base = g * 8;
  const int hd = lane / GROUP;
  float4 as4 = *reinterpret_cast<const float4*>(asv + lane * 4);
  float4 ad4 = *reinterpret_cast<const float4*>(adv + lane * 4);
#pragma unroll
  for (int i = 0; i < 8; ++i) {
    uint2 raw = *reinterpret_cast<const uint2*>(h + (size_t)(base + i) * 256 + lane * 4);
    float f0 = __uint_as_float(raw.x << 16);
    float f1 = __uint_as_float(raw.x & 0xFFFF0000u);
    float f2 = __uint_as_float(raw.y << 16);
    float f3 = __uint_as_float(raw.y & 0xFFFF0000u);
    *reinterpret_cast<float4*>(&hs[wid][i][lane * 4]) = make_float4(f0, f1, f2, f3);
    float ps = f0 * as4.x + f1 * as4.y + f2 * as4.z + f3 * as4.w;
    float pd = f0 * ad4.x + f1 * ad4.y + f2 * ad4.z + f3 * ad4.w;
#pragma unroll
    for (int o = GROUP / 2; o >= 1; o >>= 1) {
      ps += __shfl_xor(ps, o);
      pd += __shfl_xor(pd, o);
    }
    if ((lane & (GROUP - 1)) == 0) {
      attS[wid][i][hd] = ps;
      attD[wid][i][hd] = pd;
    }
  }
  __syncthreads();
  const float4 gv = *reinterpret_cast<const float4*>(lng + lane * 4);
  const float4 bv = *reinterpret_cast<const float4*>(lnb + lane * 4);
  const float4 biasv = *reinterpret_cast<const float4*>(bias + lane * 4);
  for (int i = 0; i < 8; ++i) {
    float ad = attD[wid][i][hd];
    float e[8];
    float mx = -1e30f;
#pragma unroll
    for (int j = 0; j < 8; ++j) {
      float v = attS[wid][j][hd] + ad;
      v = v > 0.f ? v : 0.2f * v;
      e[j] = v;
      mx = fmaxf(mx, v);
    }
    float sum = 0.f;
#pragma unroll
    for (int j = 0; j < 8; ++j) { e[j] = expf(e[j] - mx); sum += e[j]; }
    float inv = 1.f / (sum + 1e-16f);
    float a0 = 0, a1 = 0, a2 = 0, a3 = 0;
#pragma unroll
    for (int j = 0; j < 8; ++j) {
      float wj = e[j] * inv;
      float4 hv = *reinterpret_cast<const float4*>(&hs[wid][j][lane * 4]);
      a0 += wj * hv.x; a1 += wj * hv.y; a2 += wj * hv.z; a3 += wj * hv.w;
    }
    float4 xr = *reinterpret_cast<const float4*>(x + (size_t)(base + i) * 256 + lane * 4);
    float v0 = elu_f(a0 + biasv.x) + xr.x;
    float v1 = elu_f(a1 + biasv.y) + xr.y;
    float v2 = elu_f(a2 + biasv.z) + xr.z;
    float v3 = elu_f(a3 + biasv.w) + xr.w;
    float s = v0 + v1 + v2 + v3;
    float s2 = v0 * v0 + v1 * v1 + v2 * v2 + v3 * v3;
    s = warp_sum(s); s2 = warp_sum(s2);
    float mu = s * (1.f / 256.f);
    float var = s2 * (1.f / 256.f) - mu * mu;
    float rs = rsqrtf(var + 1e-5f);
    float4 o;
    o.x = (v0 - mu) * rs * gv.x + bv.x;
    o.y = (v1 - mu) * rs * gv.y + bv.y;
    o.z = (v2 - mu) * rs * gv.z + bv.z;
    o.w = (v3 - mu) * rs * gv.w + bv.w;
    *reinterpret_cast<float4*>(x + (size_t)(base + i) * 256 + lane * 4) = o;
  }
}

__global__ __launch_bounds__(256) void pool_readout(const float* __restrict__ x,
    const float* __restrict__ rw, const float* __restrict__ rb,
    float* __restrict__ out) {
  int g = (blockIdx.x * blockDim.x + threadIdx.x) >> 6;
  int lane = threadIdx.x & 63;
  if (g >= NG) return;
  float a0 = 0, a1 = 0, a2 = 0, a3 = 0;
#pragma unroll
  for (int j = 0; j < 8; ++j) {
    float4 v = *reinterpret_cast<const float4*>(x + (size_t)(g * 8 + j) * 256 + lane * 4);
    a0 += v.x; a1 += v.y; a2 += v.z; a3 += v.w;
  }
  float4 w = *reinterpret_cast<const float4*>(rw + lane * 4);
  float p = (a0 * w.x + a1 * w.y + a2 * w.z + a3 * w.w) * 0.125f;
  p = warp_sum(p);
  if (lane == 0) out[g] = 1.f / (1.f + expf(-(p + rb[0])));
}

extern "C" void kernel_launch(void* const* d_in, const int* in_sizes, int n_in,
                              void* d_out, int out_size, void* d_ws, size_t ws_size,
                              hipStream_t stream) {
  const int* cat_ids = (const int*)d_in[0];
  const float* vf = (const float*)d_in[1];
  const float* cat_table = (const float*)d_in[4];
  const float* vp_w1 = (const float*)d_in[5];
  const float* vp_b1 = (const float*)d_in[6];
  const float* vp_w2 = (const float*)d_in[7];
  const float* vp_b2 = (const float*)d_in[8];
  const float* vp_lng = (const float*)d_in[9];
  const float* vp_lnb = (const float*)d_in[10];
  const float* c0_w = (const float*)d_in[11];
  const float* c0_as = (const float*)d_in[12];
  const float* c0_ad = (const float*)d_in[13];
  const float* c0_b = (const float*)d_in[14];
  const float* ln0_g = (const float*)d_in[15];
  const float* ln0_b = (const float*)d_in[16];
  const float* c1_w = (const float*)d_in[17];
  const float* c1_as = (const float*)d_in[18];
  const float* c1_ad = (const float*)d_in[19];
  const float* c1_b = (const float*)d_in[20];
  const float* ln1_g = (const float*)d_in[21];
  const float* ln1_b = (const float*)d_in[22];
  const float* ro_w = (const float*)d_in[23];
  const float* ro_b = (const float*)d_in[24];
  float* out = (float*)d_out;

  char* ws = (char*)d_ws;
  ushort* w1b = (ushort*)ws;   ws += (size_t)512 * 2048 * 2;
  ushort* w2b = (ushort*)ws;   ws += (size_t)128 * 512 * 2;
  ushort* c0wb = (ushort*)ws;  ws += (size_t)256 * 256 * 2;
  ushort* c1wb = (ushort*)ws;  ws += (size_t)256 * 256 * 2;
  ushort* v1b = (ushort*)ws;   ws += (size_t)NN * 512 * 2;
  ushort* v2b = (ushort*)ws;   ws += (size_t)NN * 128 * 2;
  ushort* hbb = (ushort*)ws;   ws += (size_t)NN * 256 * 2;
  float* xb = (float*)ws;

  dim3 b256(256);
  const int RB = (NN + 63) / 64;  // 1563 row blocks of 64

  cvt_bf16<<<1024, b256, 0, stream>>>(vp_w1, w1b, 512 * 2048 / 4);
  cvt_bf16<<<64, b256, 0, stream>>>(vp_w2, w2b, 128 * 512 / 4);
  cvt_bf16<<<64, b256, 0, stream>>>(c0_w, c0wb, 256 * 256 / 4);
  cvt_bf16<<<64, b256, 0, stream>>>(c1_w, c1wb, 256 * 256 / 4);

  // v1 = relu(vf @ w1^T + b1): 64x256 tiles, 2 col-blocks paired on same XCD
  gemm_f32a<true, true><<<2 * RB, b256, 0, stream>>>(vf, w1b, vp_b1, v1b,
                                                     NN, 2048, 512, RB);
  // v2 = v1 @ w2^T + b2
  gemm_bf16a<false><<<(NN + 127) / 128, b256, 0, stream>>>(v1b, w2b, vp_b2, v2b,
                                                           NN, 512, 128);
  ln_concat<<<(NN * 64 + 255) / 256, b256, 0, stream>>>(v2b, vp_lng, vp_lnb,
                                                        cat_ids, cat_table, xb);

  gemm_f32a<false, false><<<RB, b256, 0, stream>>>(xb, c0wb, nullptr, hbb,
                                                   NN, 256, 256, 0);
  gat_fused<4><<<NG / 4, b256, 0, stream>>>(hbb, c0_as, c0_ad, c0_b, ln0_g, ln0_b, xb);

  gemm_f32a<false, false><<<RB, b256, 0, stream>>>(xb, c1wb, nullptr, hbb,
                                                   NN, 256, 256, 0);
  gat_fused<1><<<NG / 4, b256, 0, stream>>>(hbb, c1_as, c1_ad, c1_b, ln1_g, ln1_b, xb);

  pool_readout<<<NG / 4, b256, 0, stream>>>(xb, ro_w, ro_b, out);
}